// Round 6
// baseline (959.540 us; speedup 1.0000x reference)
//
#include <hip/hip_runtime.h>
#include <math.h>

#define HORIZON 15
#define PAD 7
#define CIN 48
#define C2 12
#define LAT 6
#define EPS 1e-5f
#define NREP 16

typedef __bf16 bf16x8 __attribute__((ext_vector_type(8)));
typedef float f32x4 __attribute__((ext_vector_type(4)));
typedef unsigned short ushort8v __attribute__((ext_vector_type(8)));
typedef unsigned short ushortT;

// bf16 split: v ~= hi + lo with hi = bf16(v), lo = bf16(v - hi)
__device__ inline void bfsplit(float v, ushortT& h, ushortT& l) {
    __bf16 bh = (__bf16)v;
    float fh = (float)bh;
    __bf16 bl = (__bf16)(v - fh);
    h = __builtin_bit_cast(ushortT, bh);
    l = __builtin_bit_cast(ushortT, bl);
}

// ---------------------------------------------------------------------------
// prep: dense banded split weight matrices (n-major, k-contiguous, padded),
// w3t for tail, rfft trig table.
// W1: [768][736]  n = l*48+co (<720), k = ci*15+t (<720)
// W2: [256][736]  n = l*12+co (<180), k = t*48+ci (<720)
// ---------------------------------------------------------------------------
__global__ void prep_kernel(const float* __restrict__ w1, const float* __restrict__ w2,
                            const float* __restrict__ w3,
                            ushortT* __restrict__ w1h, ushortT* __restrict__ w1l,
                            ushortT* __restrict__ w2h, ushortT* __restrict__ w2l,
                            float* __restrict__ w3t, float* __restrict__ trig) {
    int idx = blockIdx.x * blockDim.x + threadIdx.x;
    const int n1 = 768 * 736;
    const int n2 = 256 * 736;
    const int n3 = C2 * HORIZON * LAT;
    if (idx < n1) {
        int n = idx / 736, k = idx % 736;
        float v = 0.f;
        if (n < 720 && k < 720) {
            int l = n / 48, co = n % 48, ci = k / 15, t = k % 15;
            int d = t - l;
            if (d >= -PAD && d <= PAD) v = w1[(co * CIN + ci) * HORIZON + (d + PAD)];
        }
        ushortT h, lo; bfsplit(v, h, lo);
        w1h[idx] = h; w1l[idx] = lo;
    } else if (idx < n1 + n2) {
        int j = idx - n1;
        int n = j / 736, k = j % 736;
        float v = 0.f;
        if (n < 180 && k < 720) {
            int l = n / 12, co = n % 12, t = k / 48, ci = k % 48;
            int d = t - l;
            if (d >= -PAD && d <= PAD) v = w2[(co * CIN + ci) * HORIZON + (d + PAD)];
        }
        ushortT h, lo; bfsplit(v, h, lo);
        w2h[j] = h; w2l[j] = lo;
    } else if (idx < n1 + n2 + n3) {
        int j = idx - n1 - n2;
        int co = j % LAT; int r = j / LAT; int k = r % HORIZON; int ci = r / HORIZON;
        w3t[j] = w3[(co * C2 + ci) * HORIZON + k];
    } else if (idx < n1 + n2 + n3 + 7 * HORIZON) {
        int j = idx - (n1 + n2 + n3);
        int l = j % HORIZON; int f = j / HORIZON + 1;
        double ang = -2.0 * 3.14159265358979323846 * (double)(f * l) / 15.0;
        trig[j * 2]     = (float)cos(ang);
        trig[j * 2 + 1] = (float)sin(ang);
    }
}

// ---------------------------------------------------------------------------
// split_x: x f32 -> (xh, xl) bf16 split pair. Memory-bound pass.
// Thread 0 zeroes the 32-half tail pad (GEMM kstep 22 reads 16 halfs past
// the last row; pad must be finite/zero so 0-rows of B annihilate it).
// ---------------------------------------------------------------------------
__global__ __launch_bounds__(256) void split_x_kernel(const float* __restrict__ in,
                                                      ushortT* __restrict__ oh,
                                                      ushortT* __restrict__ ol, long n) {
    long i = ((long)blockIdx.x * 256 + threadIdx.x) * 8;
    if (i >= n) return;
    float4 u0 = *(const float4*)(in + i);
    float4 u1 = *(const float4*)(in + i + 4);
    float f[8] = {u0.x, u0.y, u0.z, u0.w, u1.x, u1.y, u1.z, u1.w};
    ushort8v h, l;
#pragma unroll
    for (int j = 0; j < 8; j++) { ushortT hh, ll; bfsplit(f[j], hh, ll); h[j] = hh; l[j] = ll; }
    *(ushort8v*)(oh + i) = h;
    *(ushort8v*)(ol + i) = l;
    if (i == 0) {
#pragma unroll
        for (int j = 0; j < 32; j++) { oh[n + j] = 0; ol[n + j] = 0; }
    }
}

// ---------------------------------------------------------------------------
// split_bn: y1 f32 -> BN1+ELU -> (y1h, y1l) bf16 split pair.
// Channel of element k (k = i%720) is k%48 = i%48 (720%48==0); with i = 8j
// the 8 channels c0..c0+7 never wrap (48%8==0). Identical arithmetic to the
// old fused-BN staging: fmaf(v,sc,sh) -> elu -> bfsplit.
// ---------------------------------------------------------------------------
__global__ __launch_bounds__(256) void split_bn_kernel(const float* __restrict__ in,
                                                       const float* __restrict__ bn,
                                                       ushortT* __restrict__ oh,
                                                       ushortT* __restrict__ ol, long n) {
    long i = ((long)blockIdx.x * 256 + threadIdx.x) * 8;
    if (i >= n) return;
    const int c0 = (int)(i % 48);
    float4 q[4];
#pragma unroll
    for (int m = 0; m < 4; m++) q[m] = *(const float4*)(bn + c0 * 2 + m * 4);
    float4 u0 = *(const float4*)(in + i);
    float4 u1 = *(const float4*)(in + i + 4);
    float f[8] = {u0.x, u0.y, u0.z, u0.w, u1.x, u1.y, u1.z, u1.w};
    ushort8v h, l;
#pragma unroll
    for (int j = 0; j < 8; j++) {
        float sc = (j & 1) ? q[j >> 1].z : q[j >> 1].x;
        float sh = (j & 1) ? q[j >> 1].w : q[j >> 1].y;
        float hv = fmaf(f[j], sc, sh);
        float v = hv > 0.f ? hv : expm1f(hv);
        ushortT hh, ll; bfsplit(v, hh, ll); h[j] = hh; l[j] = ll;
    }
    *(ushort8v*)(oh + i) = h;
    *(ushort8v*)(ol + i) = l;
    if (i == 0) {
#pragma unroll
        for (int j = 0; j < 32; j++) { oh[n + j] = 0; ol[n + j] = 0; }
    }
}

// ---------------------------------------------------------------------------
// Pure split-precision bf16 MFMA GEMM:  acc = Ah*Bh + Al*Bh + Ah*Bl
//
// Round-5 post-mortem: asm-register A-prefetch raced (regalloc copies read
// the dst before the load lands -> tripwire nondeterminism). Root restructure
// instead: A arrives PRE-SPLIT (split_x / split_bn passes), so the K-loop is
// pure DMA -> ds_read -> MFMA (m97-proven shape), using only the mechanisms
// that were deterministic in rounds 1-4: global_load_lds + counted
// s_waitcnt vmcnt + raw s_barrier. No C-loaded prefetch registers, no asm
// loads, no VALU split chain in the loop.
//   * per stage (wave): 4 A-DMA (2 rowhalves x h/l) + 4 B-DMA = 8 vmem ops
//   * double-buffered LDS (64KB) -> 2 blocks/CU; WAITN(8) leaves the next
//     stage in flight across the barrier (never vmcnt(0) in the loop)
//   * A LDS layout: [wave][d][lane*8 halfs]; fragment read at
//     (lr*4+lq)*8 is a permutation of contiguous 16B chunks (conflict-free)
// Stats layout PLANAR: s_stats[c]=sum, s_stats[CSTAT+c]=sumsq.
// ---------------------------------------------------------------------------
#define SBAR() asm volatile("s_barrier" ::: "memory")
#define WAITN(N) asm volatile("s_waitcnt vmcnt(" #N ")" ::: "memory")
#define GLDS16(SRC, DST)                                                      \
    __builtin_amdgcn_global_load_lds(                                         \
        (const __attribute__((address_space(1))) void*)(SRC),                 \
        (__attribute__((address_space(3))) void*)(DST), 16, 0, 0)

template <int NFRAG, int CSTAT, int NCG>
__global__ __launch_bounds__(256, 2)
void gemm_bf16(const ushortT* __restrict__ Ah, const ushortT* __restrict__ Al,
               const ushortT* __restrict__ Bh, const ushortT* __restrict__ Bl,
               float* __restrict__ Y, int ldy, int nreal,
               float* __restrict__ stats) {
    // LDS: per buffer 32KB (A 16KB + B 16KB); 2 buffers = 64KB.
    __shared__ __attribute__((aligned(16))) ushortT s_a[2][2][4096]; // [buf][h/l][w*1024+d*512+...]
    __shared__ __attribute__((aligned(16))) ushortT s_b[2][2][4096]; // [buf][h/l][nb*512+...]
    __shared__ float s_stats[2 * CSTAT];

    const int tid = threadIdx.x;
    const int w = tid >> 6, lane = tid & 63;
    const int lr = lane & 15, lq = lane >> 4;
    if (tid < 2 * CSTAT) s_stats[tid] = 0.f;
    __syncthreads();

    // XCD-aware decode: col-group fastest within one XCD's slot stream.
    const int bid = blockIdx.x;
    const int xcd = bid & 7, s = bid >> 3;
    const int rpx = (gridDim.x >> 3) / NCG;      // row-blocks per XCD
    const int col = s % NCG;
    const int rowblk = xcd * rpx + s / NCG;
    const long m_base = (long)rowblk * 128;
    const int n0 = col * (NFRAG * 16);

    // per-lane global sources.
    // A DMA op d covers rows w*32+d*16+(lane>>2), halfs k0+(lane&3)*8.
    const ushortT* asrc = Ah + (m_base + w * 32 + (lane >> 2)) * 720L + (lane & 3) * 8;
    const long adelta = Al - Ah;
    // B DMA op j covers cols n0+(w*2+j)*16+lr, halfs k0+lq*8.
    const ushortT* bsrc[2];
#pragma unroll
    for (int j = 0; j < 2; j++)
        bsrc[j] = Bh + (long)(n0 + (w * 2 + j) * 16 + lr) * 736 + lq * 8;
    const long bdelta = Bl - Bh;

    f32x4 acc[2][NFRAG];
#pragma unroll
    for (int i = 0; i < 2; i++)
#pragma unroll
        for (int jf = 0; jf < NFRAG; jf++) acc[i][jf] = (f32x4){0.f, 0.f, 0.f, 0.f};

// stage kstep KS into buffer BUF: exactly 8 vmem ops per wave.
#define ISSUE(KS, BUF)                                                        \
    do {                                                                      \
        const long k0_ = (KS) * 32;                                           \
        _Pragma("unroll")                                                     \
        for (int j_ = 0; j_ < 2; j_++) {                                      \
            const ushortT* g_ = bsrc[j_] + k0_;                               \
            GLDS16(g_, &s_b[BUF][0][(w * 2 + j_) * 512]);                     \
            GLDS16(g_ + bdelta, &s_b[BUF][1][(w * 2 + j_) * 512]);            \
        }                                                                     \
        _Pragma("unroll")                                                     \
        for (int d_ = 0; d_ < 2; d_++) {                                      \
            const ushortT* g_ = asrc + d_ * (16 * 720L) + k0_;                \
            GLDS16(g_, &s_a[BUF][0][w * 1024 + d_ * 512]);                    \
            GLDS16(g_ + adelta, &s_a[BUF][1][w * 1024 + d_ * 512]);           \
        }                                                                     \
    } while (0)

#define COMPUTE(BUF)                                                          \
    do {                                                                      \
        const int af_ = w * 1024 + (lr * 4 + lq) * 8;                         \
        bf16x8 ah0 = *(const bf16x8*)(&s_a[BUF][0][af_]);                     \
        bf16x8 ah1 = *(const bf16x8*)(&s_a[BUF][0][af_ + 512]);               \
        bf16x8 al0 = *(const bf16x8*)(&s_a[BUF][1][af_]);                     \
        bf16x8 al1 = *(const bf16x8*)(&s_a[BUF][1][af_ + 512]);               \
        __builtin_amdgcn_s_setprio(1);                                        \
        _Pragma("unroll")                                                     \
        for (int fc = 0; fc < NFRAG; fc++) {                                  \
            bf16x8 bhf = *(const bf16x8*)(&s_b[BUF][0][fc * 512 + lane * 8]); \
            bf16x8 blf = *(const bf16x8*)(&s_b[BUF][1][fc * 512 + lane * 8]); \
            acc[0][fc] = __builtin_amdgcn_mfma_f32_16x16x32_bf16(             \
                ah0, bhf, acc[0][fc], 0, 0, 0);                               \
            acc[0][fc] = __builtin_amdgcn_mfma_f32_16x16x32_bf16(             \
                al0, bhf, acc[0][fc], 0, 0, 0);                               \
            acc[0][fc] = __builtin_amdgcn_mfma_f32_16x16x32_bf16(             \
                ah0, blf, acc[0][fc], 0, 0, 0);                               \
            acc[1][fc] = __builtin_amdgcn_mfma_f32_16x16x32_bf16(             \
                ah1, bhf, acc[1][fc], 0, 0, 0);                               \
            acc[1][fc] = __builtin_amdgcn_mfma_f32_16x16x32_bf16(             \
                al1, bhf, acc[1][fc], 0, 0, 0);                               \
            acc[1][fc] = __builtin_amdgcn_mfma_f32_16x16x32_bf16(             \
                ah1, blf, acc[1][fc], 0, 0, 0);                               \
        }                                                                     \
        __builtin_amdgcn_s_setprio(0);                                        \
    } while (0)

    // KSTEPS = 23 (k = 0..736; A halfs >=720 read the zeroed pad / next row,
    // annihilated by B's zero rows; B is 736-wide zero-padded).
    // Ledger: each stage = 8 ops. Steady state: 16 outstanding; WAITN(8)
    // completes the oldest stage and leaves the next in flight.
    ISSUE(0, 0);
    ISSUE(1, 1);
#pragma unroll 1
    for (int k2 = 0; k2 < 20; k2 += 2) {
        WAITN(8); SBAR();
        COMPUTE(0);
        SBAR();
        ISSUE(k2 + 2, 0);
        WAITN(8); SBAR();
        COMPUTE(1);
        SBAR();
        ISSUE(k2 + 3, 1);
    }
    // ks = 20 (buf0): issue last stage 22 into buf0 after its reads complete
    WAITN(8); SBAR();
    COMPUTE(0);
    SBAR();
    ISSUE(22, 0);
    // ks = 21 (buf1)
    WAITN(8); SBAR();
    COMPUTE(1);
    SBAR();
    // ks = 22 (buf0)
    WAITN(0); SBAR();
    COMPUTE(0);

#undef ISSUE
#undef COMPUTE

    // ---- epilogue: store + per-channel stats (PLANAR layout) ----
    // C/D layout: col = lane&15, row = (lane>>4)*4 + reg
    float ps[3] = {0.f, 0.f, 0.f}, qs[3] = {0.f, 0.f, 0.f};
#pragma unroll
    for (int fc = 0; fc < NFRAG; fc++) {
        int colY = n0 + fc * 16 + lr;
        int j = fc % 3;
#pragma unroll
        for (int fr = 0; fr < 2; fr++) {
#pragma unroll
            for (int r = 0; r < 4; r++) {
                float v = acc[fr][fc][r];
                long row = m_base + w * 32 + fr * 16 + lq * 4 + r;
                if (colY < nreal) Y[row * (long)ldy + colY] = v;
                ps[j] += v;
                qs[j] = fmaf(v, v, qs[j]);
            }
        }
    }
#pragma unroll
    for (int j = 0; j < 3; j++) {
        int c = (n0 + lr + 16 * j) % CSTAT;
        atomicAdd(&s_stats[c], ps[j]);
        atomicAdd(&s_stats[CSTAT + c], qs[j]);
    }
    __syncthreads();
    if (tid < 2 * CSTAT)
        atomicAdd(&stats[(rowblk & (NREP - 1)) * 2 * CSTAT + tid], s_stats[tid]);
}

// ---------------------------------------------------------------------------
// finalize BN: planar stats [sum[0..C-1], sumsq[0..C-1]] per replica
// ---------------------------------------------------------------------------
__global__ void finalize_bn(const float* __restrict__ stats, const float* __restrict__ g,
                            const float* __restrict__ be, float* __restrict__ bn,
                            int C, float invN) {
    int c = threadIdx.x;
    if (c >= C) return;
    float s1 = 0.f, s2 = 0.f;
    for (int r = 0; r < NREP; r++) { s1 += stats[r * 2 * C + c]; s2 += stats[r * 2 * C + C + c]; }
    float m   = s1 * invN;
    float var = s2 * invN - m * m;
    float sc  = g[c] * rsqrtf(var + EPS);
    bn[c * 2]     = sc;
    bn[c * 2 + 1] = fmaf(-m, sc, be[c]);
}

// ---------------------------------------------------------------------------
// tail: BN2+ELU fused on load -> conv3 (+b3) -> rfft stats + phase linear
// ---------------------------------------------------------------------------
__global__ __launch_bounds__(256) void tail_kernel(const float* __restrict__ h2,
                                                   const float* __restrict__ w3t,
                                                   const float* __restrict__ b3,
                                                   const float* __restrict__ pw,
                                                   const float* __restrict__ trig,
                                                   const float* __restrict__ bn2,
                                                   float* __restrict__ out,
                                                   float* __restrict__ vout,
                                                   float* __restrict__ stats) {
    __shared__ float s_sum[2 * LAT];
    __shared__ float s_sq[2 * LAT];
    int t = threadIdx.x;
    if (t < 2 * LAT) { s_sum[t] = 0.f; s_sq[t] = 0.f; }
    __syncthreads();

    int id = blockIdx.x * 256 + t;
    int co = id % LAT;
    long b = id / LAT;
    const float* xr = h2 + b * (long)(C2 * HORIZON);

    float acc[HORIZON];
#pragma unroll
    for (int l = 0; l < HORIZON; l++) acc[l] = b3[co];

    for (int ci = 0; ci < C2; ci++) {
        float sc = bn2[ci * 2], sh = bn2[ci * 2 + 1];
        float xv[HORIZON];
#pragma unroll
        for (int tt = 0; tt < HORIZON; tt++) {
            float h = fmaf(xr[tt * C2 + ci], sc, sh);
            xv[tt] = h > 0.f ? h : expm1f(h);
        }
        float wv[HORIZON];
#pragma unroll
        for (int k = 0; k < HORIZON; k++) wv[k] = w3t[(ci * HORIZON + k) * LAT + co];
#pragma unroll
        for (int tt = 0; tt < HORIZON; tt++) {
            const int lo = (tt - PAD) > 0 ? (tt - PAD) : 0;
            const int hi = (tt + PAD) < (HORIZON - 1) ? (tt + PAD) : (HORIZON - 1);
#pragma unroll
            for (int l = lo; l <= hi; l++)
                acc[l] = fmaf(xv[tt], wv[tt - l + PAD], acc[l]);
        }
    }

    float ssum = 0.f;
#pragma unroll
    for (int l = 0; l < HORIZON; l++) ssum += acc[l];
    float b_off = ssum * (1.f / 15.f);

    float psum = 0.f, fnum = 0.f;
#pragma unroll
    for (int j = 0; j < 7; j++) {
        float re = 0.f, im = 0.f;
#pragma unroll
        for (int l = 0; l < HORIZON; l++) {
            float c = trig[(j * HORIZON + l) * 2];
            float s = trig[(j * HORIZON + l) * 2 + 1];
            re = fmaf(acc[l], c, re);
            im = fmaf(acc[l], s, im);
        }
        float p = fmaf(re, re, im * im);
        psum += p;
        fnum = fmaf((float)(j + 1), p, fnum);
    }
    float f = fnum / psum;
    float a = 2.f * sqrtf(psum) * (1.f / 15.f);

    float* orow = out + b * 24;
    orow[6 + co]  = f;
    orow[12 + co] = a;
    orow[18 + co] = b_off;

    float v0 = 0.f, v1 = 0.f;
#pragma unroll
    for (int l = 0; l < HORIZON; l++) {
        v0 = fmaf(acc[l], pw[(co * 2 + 0) * HORIZON + l], v0);
        v1 = fmaf(acc[l], pw[(co * 2 + 1) * HORIZON + l], v1);
    }
    vout[b * 12 + co * 2]     = v0;
    vout[b * 12 + co * 2 + 1] = v1;
    atomicAdd(&s_sum[co * 2], v0);
    atomicAdd(&s_sq[co * 2], v0 * v0);
    atomicAdd(&s_sum[co * 2 + 1], v1);
    atomicAdd(&s_sq[co * 2 + 1], v1 * v1);

    __syncthreads();
    float* st = stats + (blockIdx.x & (NREP - 1)) * 2 * (2 * LAT);
    if (t < 2 * LAT) {
        atomicAdd(&st[t], s_sum[t]);
        atomicAdd(&st[2 * LAT + t], s_sq[t]);
    }
}

// ---------------------------------------------------------------------------
__global__ void phase_kernel(const float* __restrict__ v, const float* __restrict__ bnP,
                             float* __restrict__ out, long B) {
    long b = (long)blockIdx.x * 256 + threadIdx.x;
    if (b >= B) return;
#pragma unroll
    for (int co = 0; co < LAT; co++) {
        float v0 = v[b * 12 + co * 2];
        float v1 = v[b * 12 + co * 2 + 1];
        int c0 = co * 2, c1 = co * 2 + 1;
        v0 = fmaf(v0, bnP[c0 * 2], bnP[c0 * 2 + 1]);
        v1 = fmaf(v1, bnP[c1 * 2], bnP[c1 * 2 + 1]);
        out[b * 24 + co] = atan2f(v1, v0) * 0.15915494309189535f;
    }
}

// ---------------------------------------------------------------------------
extern "C" void kernel_launch(void* const* d_in, const int* in_sizes, int n_in,
                              void* d_out, int out_size, void* d_ws, size_t ws_size,
                              hipStream_t stream) {
    const float* x   = (const float*)d_in[0];
    const float* w1  = (const float*)d_in[1];
    const float* g1  = (const float*)d_in[3];
    const float* be1 = (const float*)d_in[4];
    const float* w2  = (const float*)d_in[5];
    const float* g2  = (const float*)d_in[7];
    const float* be2 = (const float*)d_in[8];
    const float* w3  = (const float*)d_in[9];
    const float* b3  = (const float*)d_in[10];
    const float* pw  = (const float*)d_in[11];
    const float* pg  = (const float*)d_in[13];
    const float* pbe = (const float*)d_in[14];
    float* out = (float*)d_out;

    long B = (long)in_sizes[0] / (CIN * HORIZON);   // 65536
    const long NA = B * 720;                        // A elements (48*15 = 720)

    // Workspace layout (16B-aligned segments):
    ushortT* w1h = (ushortT*)d_ws;          // 768*736
    ushortT* w1l = w1h + 768 * 736;
    ushortT* w2h = w1l + 768 * 736;         // 256*736
    ushortT* w2l = w2h + 256 * 736;
    ushortT* xh  = w2l + 256 * 736;         // NA + 32 pad  (reused as y1h)
    ushortT* xl  = xh + (NA + 32);          // NA + 32 pad  (reused as y1l)
    float* y1 = (float*)(xl + (NA + 32));   // B*720
    float* y2 = y1 + NA;                    // B*180
    float* vv = y2 + B * 180;               // B*12
    float* stats1 = vv + B * 12;            // NREP*96
    float* stats2 = stats1 + NREP * 96;     // NREP*24
    float* statsP = stats2 + NREP * 24;     // NREP*24
    float* bn1 = statsP + NREP * 24;        // 96
    float* bn2 = bn1 + 96;                  // 24
    float* bnP = bn2 + 24;                  // 24
    float* w3t = bnP + 24;                  // 1080
    float* trig = w3t + C2 * HORIZON * LAT; // 210

    hipMemsetAsync(stats1, 0, NREP * (96 + 24 + 24) * sizeof(float), stream);

    const int prep_total = 768 * 736 + 256 * 736 + C2 * HORIZON * LAT + 7 * HORIZON;
    prep_kernel<<<(prep_total + 255) / 256, 256, 0, stream>>>(w1, w2, w3, w1h, w1l, w2h, w2l, w3t, trig);

    // pre-split x -> xh/xl (bit-identical bfsplit to the old in-loop split)
    split_x_kernel<<<(int)(NA / 8 / 256), 256, 0, stream>>>(x, xh, xl, NA);

    // GEMM1: pure bf16 GEMM on pre-split A. 6 col-groups x 512 row-blocks.
    gemm_bf16<8, 48, 6><<<3072, 256, 0, stream>>>(
        xh, xl, w1h, w1l, y1, 720, 720, stats1);
    finalize_bn<<<1, 64, 0, stream>>>(stats1, g1, be1, bn1, CIN, 1.f / (float)(B * HORIZON));

    // BN1+ELU+split: y1 -> y1h/y1l (aliases xh/xl; x splits are dead now)
    split_bn_kernel<<<(int)(NA / 8 / 256), 256, 0, stream>>>(y1, bn1, xh, xl, NA);

    // GEMM2: pure bf16 GEMM. 2 col-groups of 96 real cols.
    gemm_bf16<6, 12, 2><<<1024, 256, 0, stream>>>(
        xh, xl, w2h, w2l, y2, 180, 180, stats2);
    finalize_bn<<<1, 64, 0, stream>>>(stats2, g2, be2, bn2, C2, 1.f / (float)(B * HORIZON));

    // tail: BN2+ELU fused on load
    tail_kernel<<<(int)(B * LAT / 256), 256, 0, stream>>>(y2, w3t, b3, pw, trig, bn2, out, vv, statsP);
    finalize_bn<<<1, 64, 0, stream>>>(statsP, pg, pbe, bnP, 2 * LAT, 1.f / (float)B);

    phase_kernel<<<(int)((B + 255) / 256), 256, 0, stream>>>(vv, bnP, out, B);
}